// Round 8
// baseline (1283.751 us; speedup 1.0000x reference)
//
#include <hip/hip_runtime.h>
#include <math.h>

constexpr int CB  = 8;     // batches
constexpr int CN  = 8192;  // points
constexpr int CS  = 512;   // npoint
constexpr int CK  = 32;    // nsample
constexpr int CD  = 128;   // dim
constexpr int CF  = 256;   // dff
constexpr int CO  = 256;   // dim_out
constexpr float CEPS = 1e-5f;

typedef __attribute__((ext_vector_type(8)))  short short8;
typedef __attribute__((ext_vector_type(4)))  float f32x4;
typedef __attribute__((ext_vector_type(16))) float f32x16;
#define MFMA16(a,b,c) __builtin_amdgcn_mfma_f32_16x16x32_bf16(a,b,c,0,0,0)
#define MFMA32(a,b,c) __builtin_amdgcn_mfma_f32_32x32x16_bf16(a,b,c,0,0,0)

__device__ __forceinline__ ushort f2b(float f){
  unsigned u = __builtin_bit_cast(unsigned, f);
  u = u + 0x7fffu + ((u >> 16) & 1u);
  return (ushort)(u >> 16);
}

// DPP permute of a u64, masked lanes keep their own value (old = self).
template<int CTRL, int RM>
__device__ __forceinline__ unsigned long long dpp64(unsigned long long k){
  int lo = (int)(unsigned)k;
  int hi = (int)(unsigned)(k >> 32);
  int plo = __builtin_amdgcn_update_dpp(lo, lo, CTRL, RM, 0xF, false);
  int phi = __builtin_amdgcn_update_dpp(hi, hi, CTRL, RM, 0xF, false);
  return ((unsigned long long)(unsigned)phi << 32) | (unsigned)plo;
}
// full-wave max; result valid in lane 63
__device__ __forceinline__ unsigned long long wave_max64(unsigned long long k){
  unsigned long long p;
  p = dpp64<0xB1,0xF>(k); k = p > k ? p : k;   // i^1
  p = dpp64<0x4E,0xF>(k); k = p > k ? p : k;   // i^2
  p = dpp64<0x140,0xF>(k); k = p > k ? p : k;  // row mirror
  p = dpp64<0x141,0xF>(k); k = p > k ? p : k;  // half mirror -> row(16) max everywhere
  p = dpp64<0x142,0xA>(k); k = p > k ? p : k;  // bcast15 -> rows 1,3
  p = dpp64<0x143,0xC>(k); k = p > k ? p : k;  // bcast31 -> rows 2,3 ; lane63 full
  return k;
}
__device__ __forceinline__ unsigned long long wave_min64(unsigned long long k){
  unsigned long long p;
  p = dpp64<0xB1,0xF>(k); k = p < k ? p : k;
  p = dpp64<0x4E,0xF>(k); k = p < k ? p : k;
  p = dpp64<0x140,0xF>(k); k = p < k ? p : k;
  p = dpp64<0x141,0xF>(k); k = p < k ? p : k;
  p = dpp64<0x142,0xA>(k); k = p < k ? p : k;
  p = dpp64<0x143,0xC>(k); k = p < k ? p : k;
  return k;
}
// butterfly over 16 replicated values in lanes (l&15) -> all lanes get max.
// steps: xor1, xor2, row_ror:4, row_ror:8 (rotations compose to cover all 16)
__device__ __forceinline__ unsigned long long hex_max64(unsigned long long k){
  unsigned long long p;
  p = dpp64<0xB1,0xF>(k);  k = p > k ? p : k;   // i^1
  p = dpp64<0x4E,0xF>(k);  k = p > k ? p : k;   // i^2 -> aligned quad
  p = dpp64<0x124,0xF>(k); k = p > k ? p : k;   // row_ror:4 -> two quads
  p = dpp64<0x128,0xF>(k); k = p > k ? p : k;   // row_ror:8 -> all 16
  return k;
}
__device__ __forceinline__ unsigned long long quad_min64(unsigned long long k){
  unsigned long long p;
  p = dpp64<0xB1,0xF>(k); k = p < k ? p : k;
  p = dpp64<0x4E,0xF>(k); k = p < k ? p : k;
  return k;
}

// ---------------------------------------------------------------- FPS + wprep + transpose fused
// blocks 0..7: FPS (1024 thr, 8 pts/thread -> 4 waves/SIMD TLP).
// blocks 8..71: weight prep. blocks 72+: feature transpose (riders).
__global__ __launch_bounds__(1024)
void fps_fused_kernel(const float* __restrict__ xyz, int* __restrict__ fps_idx,
                      const float* __restrict__ features, float* __restrict__ featT,
                      const float* __restrict__ wqkv, const float* __restrict__ wo,
                      const float* __restrict__ w1,   const float* __restrict__ w2,
                      ushort* __restrict__ wfrag)
{
#pragma clang fp contract(off)
  __shared__ __align__(16) float4 p4[CN];
  __shared__ unsigned long long wred[2][16];
  const int bid = blockIdx.x, t = threadIdx.x;

  if (bid >= CB + 64){
    // ---- transpose role: 4 tiles of 32x32 per 1024-thread block
    if (featT == nullptr) return;
    const int tt  = (bid - CB - 64)*4 + (t >> 8);
    const int b2  = tt >> 10;
    const int rem = tt & 1023;
    const int d0  = (rem >> 8) * 32;
    const int n0  = (rem & 255) * 32;
    const int t2  = t & 255;
    const int tx  = t2 & 31, ty = t2 >> 5;     // ty in 0..7
    float* tl = ((float*)p4) + (t >> 8) * (32*33);
    const float* fb = features + (size_t)b2*CD*CN;
    #pragma unroll
    for (int r=0;r<32;r+=8) tl[(ty+r)*33 + tx] = fb[(size_t)(d0+ty+r)*CN + n0+tx];
    __syncthreads();
    float* ftb = featT + (size_t)b2*CN*CD;
    #pragma unroll
    for (int r=0;r<32;r+=8) ftb[(size_t)(n0+ty+r)*CD + d0+tx] = tl[tx*33 + (ty+r)];
    return;
  }
  if (bid >= CB){
    // ---- weight prep role -> bf16 MFMA B-fragments
    const int tid = (bid - CB)*1024 + t;       // 0..65535
    const int l = tid & 63;
    const int f = tid >> 6;                    // 0..1023
    const int L = f >> 8;
    const int r = f & 255;
    const float* src; int stride, nt, kt;
    if (r < 96)      { nt = r>>2;        kt = r&3;        src = wqkv + (size_t)L*384*128; stride = 128; }
    else if (r < 128){ nt = (r-96)>>2;   kt = (r-96)&3;   src = wo   + (size_t)L*128*128; stride = 128; }
    else if (r < 192){ nt = (r-128)>>2;  kt = (r-128)&3;  src = w1   + (size_t)L*256*128; stride = 128; }
    else             { nt = (r-192)>>3;  kt = (r-192)&7;  src = w2   + (size_t)L*128*256; stride = 256; }
    const int n = nt*16 + (l & 15);
    const int k = kt*32 + (l >> 4)*8;
    const float* p = src + (size_t)n*stride + k;
    uint4 o;
    o.x = (unsigned)f2b(p[0]) | ((unsigned)f2b(p[1])<<16);
    o.y = (unsigned)f2b(p[2]) | ((unsigned)f2b(p[3])<<16);
    o.z = (unsigned)f2b(p[4]) | ((unsigned)f2b(p[5])<<16);
    o.w = (unsigned)f2b(p[6]) | ((unsigned)f2b(p[7])<<16);
    *(uint4*)(wfrag + (size_t)tid*8) = o;
    return;
  }

  // ---- FPS role: 1024 thr x 8 pts in regs; DPP wave reduce; one barrier/iter.
  const int b = bid;
  const int w = t >> 6, lane = t & 63;
  const float* xb = xyz + (size_t)b*3*CN;
  float px[8], py[8], pz[8], dist[8];
  #pragma unroll
  for (int j=0;j<8;j++){
    const int i = t + 1024*j;
    px[j] = xb[i]; py[j] = xb[CN+i]; pz[j] = xb[2*CN+i];
    dist[j] = 1e10f;
    p4[i] = make_float4(px[j], py[j], pz[j], 0.f);
  }
  __syncthreads();
  int far = 0, par = 0;
  float4 c = p4[0];
  for (int it = 0; it < CS; ++it){
    if (t == 0) fps_idx[b*CS + it] = far;
    unsigned long long kk[8];
    #pragma unroll
    for (int j=0;j<8;j++){
      const float dx = px[j]-c.x, dy = py[j]-c.y, dz = pz[j]-c.z;
      const float d2 = (dx*dx + dy*dy) + dz*dz;
      const float nd = fminf(dist[j], d2);
      dist[j] = nd;
      kk[j] = ((unsigned long long)__builtin_bit_cast(unsigned, nd) << 32)
              | (unsigned)(8191 - (t + 1024*j));
    }
    #pragma unroll
    for (int st=1; st<8; st<<=1)
      #pragma unroll
      for (int j=0;j<8;j+=2*st)
        kk[j] = kk[j] >= kk[j+st] ? kk[j] : kk[j+st];
    const unsigned long long key = wave_max64(kk[0]);
    if (lane == 63) wred[par][w] = key;          // result lives in lane 63; no shfl
    __syncthreads();
    unsigned long long k2 = wred[par][lane & 15];
    k2 = hex_max64(k2);
    far = 8191 - (int)(k2 & 0xFFFFFFFFu);
    c = p4[far];
    par ^= 1;
  }
}

// ---------------------------------------------------------------- kNN (+ new_xyz output folded in)
__global__ __launch_bounds__(256)
void knn_kernel(const float* __restrict__ xyz, const int* __restrict__ fps_idx,
                int* __restrict__ gidx, float* __restrict__ out0)
{
#pragma clang fp contract(off)
  __shared__ unsigned long long wredk[2][4];
  const int blk = blockIdx.x, t = threadIdx.x;
  const int w = t >> 6, l = t & 63;
  const int b = blk >> 9;
  const int s = blk & 511;
  const float* xb = xyz + (size_t)b*3*CN;
  const int cidx = fps_idx[b*CS + s];
  const float cx = xb[cidx], cy = xb[CN+cidx], cz = xb[2*CN+cidx];
  const float cn2 = (cx*cx + cy*cy) + cz*cz;
  if (t == 0){
    float* o = out0 + (size_t)b*3*CS + s;
    o[0] = cx; o[CS] = cy; o[2*CS] = cz;
  }
  unsigned long long kv[32];
  #pragma unroll
  for (int j=0;j<32;j++){
    const int i = t + 256*j;
    const float x = xb[i], y = xb[CN+i], z = xb[2*CN+i];
    const float pn2 = (x*x + y*y) + z*z;
    const float dot = (cx*x + cy*y) + cz*z;
    const float d2 = (cn2 + pn2) - 2.0f*dot;
    unsigned u = __builtin_bit_cast(unsigned, d2);
    u ^= (unsigned)((int)u >> 31) | 0x80000000u;   // total order incl. negatives
    kv[j] = ((unsigned long long)u << 32) | (unsigned)i;
  }
  unsigned long long mv;
  {
    unsigned long long tmp[16];
    #pragma unroll
    for (int j=0;j<16;j++) tmp[j] = kv[j] < kv[j+16] ? kv[j] : kv[j+16];
    #pragma unroll
    for (int st=8; st>=1; st>>=1)
      #pragma unroll
      for (int j=0;j<st;j++) tmp[j] = tmp[j] < tmp[j+st] ? tmp[j] : tmp[j+st];
    mv = tmp[0];
  }
  int par = 0;
  for (int k=0;k<CK;k++){
    const unsigned long long v = wave_min64(mv);
    if (l == 63) wredk[par][w] = v;              // no shfl
    __syncthreads();
    unsigned long long k2 = wredk[par][l & 3];
    k2 = quad_min64(k2);
    const int win = (int)(k2 & 0xFFFFFFFFu);
    if (t == 0) gidx[(size_t)blk*CK + k] = win;
    if ((win & 255) == t){
      const int jw = win >> 8;
      #pragma unroll
      for (int j=0;j<32;j++) if (j == jw) kv[j] = ~0ull;
      unsigned long long tmp[16];
      #pragma unroll
      for (int j=0;j<16;j++) tmp[j] = kv[j] < kv[j+16] ? kv[j] : kv[j+16];
      #pragma unroll
      for (int st=8; st>=1; st>>=1)
        #pragma unroll
        for (int j=0;j<st;j++) tmp[j] = tmp[j] < tmp[j+st] ? tmp[j] : tmp[j+st];
      mv = tmp[0];
    }
    par ^= 1;
  }
}

// ---------------------------------------------------------------- gather + PE (4x4 register tile)
// w2s layout: [128 rows][64 dwords], float4-unit u stored at u ^ ((row>>2)&7).
// Read lane-stride was 16-way bank conflicted with linear 68-pad; swizzle -> 4-way.
__global__ __launch_bounds__(256)
void pe_kernel(const float* __restrict__ xyz, const float* __restrict__ features,
               const float* __restrict__ featT, const int* __restrict__ gidx,
               const float* __restrict__ pe_w1, const float* __restrict__ pe_b1,
               const float* __restrict__ bn_g, const float* __restrict__ bn_b,
               const float* __restrict__ bn_m, const float* __restrict__ bn_v,
               const float* __restrict__ pe_w2, const float* __restrict__ pe_b2,
               float* __restrict__ xout)
{
  __shared__ __align__(16) float w2s[CD*64];
  __shared__ __align__(16) float hr[CK*68];
  __shared__ int idxs[CK];
  __shared__ float gx[CK], gy[CK], gz[CK];
  const int g = blockIdx.x, t = threadIdx.x;
  const int b = g >> 9;
  for (int i=t; i<CD*64; i+=256){
    const int row = i>>6, c = i&63;
    const int u = (c>>2) ^ ((row>>2)&7);
    w2s[row*64 + (u<<2) + (c&3)] = pe_w2[i];
  }
  if (t < CK){
    const int id = gidx[(size_t)g*CK + t];
    idxs[t] = id;
    const float* xb = xyz + (size_t)b*3*CN;
    gx[t] = xb[id]; gy[t] = xb[CN+id]; gz[t] = xb[2*CN+id];
  }
  __syncthreads();
  for (int v=t; v<CK*64; v+=256){
    const int k = v>>6, j = v&63;
    float h = ((gx[k]*pe_w1[j*3] + gy[k]*pe_w1[j*3+1]) + gz[k]*pe_w1[j*3+2]) + pe_b1[j];
    h = (h - bn_m[j]) / sqrtf(bn_v[j] + CEPS) * bn_g[j] + bn_b[j];
    hr[k*68+j] = fmaxf(h, 0.f);
  }
  __syncthreads();
  const int kt = t >> 5, dt = t & 31;
  const int k0 = kt*4, d0 = dt*4;
  const int sw = dt & 7;                 // = ((d0+bb)>>2)&7 for bb in 0..3
  float acc[4][4];
  #pragma unroll
  for (int a=0;a<4;a++)
    #pragma unroll
    for (int bb=0;bb<4;bb++) acc[a][bb] = 0.f;
  for (int j=0;j<16;j++){
    float4 h4[4], w4[4];
    #pragma unroll
    for (int a=0;a<4;a++) h4[a] = *(const float4*)&hr[(k0+a)*68 + j*4];
    #pragma unroll
    for (int bb=0;bb<4;bb++) w4[bb] = *(const float4*)&w2s[(d0+bb)*64 + ((j ^ sw)<<2)];
    #pragma unroll
    for (int a=0;a<4;a++)
      #pragma unroll
      for (int bb=0;bb<4;bb++){
        acc[a][bb] += h4[a].x*w4[bb].x; acc[a][bb] += h4[a].y*w4[bb].y;
        acc[a][bb] += h4[a].z*w4[bb].z; acc[a][bb] += h4[a].w*w4[bb].w;
      }
  }
  const float4 b2v = *(const float4*)&pe_b2[d0];
  const float* fb  = features + (size_t)b*CD*CN;
  const float* ftb = featT ? (featT + (size_t)b*CN*CD) : nullptr;
  #pragma unroll
  for (int a=0;a<4;a++){
    const int id = idxs[k0+a];
    float4 gf;
    if (ftb) gf = *(const float4*)&ftb[(size_t)id*CD + d0];
    else gf = make_float4(fb[(size_t)(d0+0)*CN+id], fb[(size_t)(d0+1)*CN+id],
                          fb[(size_t)(d0+2)*CN+id], fb[(size_t)(d0+3)*CN+id]);
    float4 o;
    o.x = gf.x + (acc[a][0] + b2v.x);
    o.y = gf.y + (acc[a][1] + b2v.y);
    o.z = gf.z + (acc[a][2] + b2v.z);
    o.w = gf.w + (acc[a][3] + b2v.w);
    *(float4*)&xout[(size_t)g*4096 + (size_t)(k0+a)*128 + d0] = o;
  }
}

// ---------------------------------------------------------------- fused MFMA transformer: 4 layers + pool + fc
__device__ __forceinline__ void ln_inplace(float* x32s, ushort* xbv,
                                           const float* __restrict__ gamma,
                                           const float* __restrict__ beta, int t)
{
  const int r = t >> 3, j = t & 7;
  float v[16]; float s = 0.f;
  #pragma unroll
  for (int i=0;i<16;i++){ v[i] = x32s[r*132 + j + 8*i]; s += v[i]; }
  #pragma unroll
  for (int off=1; off<8; off<<=1) s += __shfl_xor(s, off);
  const float mean = s * (1.f/128.f);
  float var = 0.f;
  #pragma unroll
  for (int i=0;i<16;i++){ const float d = v[i]-mean; var += d*d; }
  #pragma unroll
  for (int off=1; off<8; off<<=1) var += __shfl_xor(var, off);
  const float inv = 1.f / sqrtf(var*(1.f/128.f) + CEPS);
  #pragma unroll
  for (int i=0;i<16;i++){
    const int d = j + 8*i;
    const float o = (v[i]-mean)*inv*gamma[d] + beta[d];
    x32s[r*132 + d] = o;
    xbv[r*136 + d] = f2b(o);
  }
}

__global__ __launch_bounds__(256, 2)
void layers_mfma_kernel(const float* __restrict__ xbuf, const ushort* __restrict__ wf,
                        const float* __restrict__ bqkv, const float* __restrict__ bo,
                        const float* __restrict__ g1, const float* __restrict__ b1v,
                        const float* __restrict__ bf1, const float* __restrict__ bf2,
                        const float* __restrict__ g2, const float* __restrict__ b2v,
                        const float* __restrict__ fc_w, const float* __restrict__ fc_b,
                        float* __restrict__ fcout)
{
  __shared__ __align__(16) float  x32s[32*132];   // fp32 residual path
  __shared__ __align__(16) ushort xbv [32*136];   // bf16 A-operand buffer
  __shared__ __align__(16) ushort qk  [32*264];   // Q|K, later FFN1 out
  __shared__ __align__(16) ushort vT  [128*40];   // V transposed [dim][token]
  __shared__ __align__(16) ushort Pb  [4*32*40];  // per-wave P scratch
  __shared__ __align__(16) float  pooled[CD];
  const int g = blockIdx.x, t = threadIdx.x;
  const int w = t>>6, l = t&63;
  const int l15 = l&15, q4 = l>>4, l31 = l&31, hi = l>>5;
  const float* xg = xbuf + (size_t)g*1024*4;

  for (int i=t;i<1024;i+=256){
    const float4 v = ((const float4*)xg)[i];
    const int r = i>>5, c = (i&31)*4;
    *(float4*)&x32s[r*132 + c] = v;
    uint2 p;
    p.x = (unsigned)f2b(v.x) | ((unsigned)f2b(v.y)<<16);
    p.y = (unsigned)f2b(v.z) | ((unsigned)f2b(v.w)<<16);
    *(uint2*)&xbv[r*136 + c] = p;
  }
  __syncthreads();

  #pragma unroll 1
  for (int L = 0; L < 4; ++L){
    const uint4*  wfv   = (const uint4*)(wf + (size_t)L*131072);
    const float* bqkvL  = bqkv + (size_t)L*3*CD;
    const float* boL    = bo   + (size_t)L*CD;
    const float* g1L    = g1   + (size_t)L*CD;
    const float* b1L    = b1v  + (size_t)L*CD;
    const float* bf1L   = bf1  + (size_t)L*CF;
    const float* bf2L   = bf2  + (size_t)L*CD;
    const float* g2L    = g2   + (size_t)L*CD;
    const float* b2L    = b2v  + (size_t)L*CD;

    // ---- QKV
    {
      short8 a[2][4];
      #pragma unroll
      for (int mt=0;mt<2;mt++)
        #pragma unroll
        for (int kt=0;kt<4;kt++)
          a[mt][kt] = __builtin_bit_cast(short8, *(const uint4*)&xbv[(l15+16*mt)*136 + kt*32 + q4*8]);
      for (int i=0;i<6;i++){
        const int nt = w + 4*i;
        const int n  = nt*16 + l15;
        f32x4 a0 = {0.f,0.f,0.f,0.f}, a1 = {0.f,0.f,0.f,0.f};
        #pragma unroll
        for (int kt=0;kt<4;kt++){
          const short8 b = __builtin_bit_cast(short8, wfv[(nt*4+kt)*64 + l]);
          a0 = MFMA16(a[0][kt], b, a0);
          a1 = MFMA16(a[1][kt], b, a1);
        }
        const float bias = bqkvL[n];
        if (nt < 16){
          #pragma unroll
          for (int i2=0;i2<4;i2++){
            qk[(q4*4+i2   )*264 + n] = f2b(a0[i2]+bias);
            qk[(q4*4+i2+16)*264 + n] = f2b(a1[i2]+bias);
          }
        } else {
          const int d = n - 256;
          uint2 p0, p1;
          p0.x = (unsigned)f2b(a0[0]+bias) | ((unsigned)f2b(a0[1]+bias)<<16);
          p0.y = (unsigned)f2b(a0[2]+bias) | ((unsigned)f2b(a0[3]+bias)<<16);
          p1.x = (unsigned)f2b(a1[0]+bias) | ((unsigned)f2b(a1[1]+bias)<<16);
          p1.y = (unsigned)f2b(a1[2]+bias) | ((unsigned)f2b(a1[3]+bias)<<16);
          *(uint2*)&vT[d*40 + q4*4]      = p0;
          *(uint2*)&vT[d*40 + 16 + q4*4] = p1;
        }
      }
    }
    __syncthreads();

    // ---- attention
    for (int hh=0; hh<2; hh++){
      const int h = 2*w + hh;
      const short8 ka = __builtin_bit_cast(short8, *(const uint4*)&qk[l31*264 + 128 + h*16 + hi*8]);
      const short8 qb = __builtin_bit_cast(short8, *(const uint4*)&qk[l31*264 +       h*16 + hi*8]);
      f32x16 s;
      #pragma unroll
      for (int i=0;i<16;i++) s[i] = 0.f;
      s = MFMA32(ka, qb, s);
      float e[16]; float mx = -1e30f;
      #pragma unroll
      for (int i=0;i<16;i++){ e[i] = s[i]*0.25f; mx = fmaxf(mx, e[i]); }
      mx = fmaxf(mx, __shfl_xor(mx, 32));
      float sum = 0.f;
      #pragma unroll
      for (int i=0;i<16;i++){ e[i] = __expf(e[i]-mx); sum += e[i]; }
      sum += __shfl_xor(sum, 32);
      const float inv = 1.f/sum;
      #pragma unroll
      for (int j=0;j<4;j++){
        uint2 p;
        p.x = (unsigned)f2b(e[4*j  ]*inv) | ((unsigned)f2b(e[4*j+1]*inv)<<16);
        p.y = (unsigned)f2b(e[4*j+2]*inv) | ((unsigned)f2b(e[4*j+3]*inv)<<16);
        *(uint2*)&Pb[w*1280 + l31*40 + j*8 + hi*4] = p;
      }
      const short8 bv = __builtin_bit_cast(short8, *(const uint4*)&vT[(h*16+l15)*40 + q4*8]);
      #pragma unroll
      for (int mt=0;mt<2;mt++){
        const short8 ap = __builtin_bit_cast(short8, *(const uint4*)&Pb[w*1280 + (l15+16*mt)*40 + q4*8]);
        f32x4 o = {0.f,0.f,0.f,0.f};
        o = MFMA16(ap, bv, o);
        #pragma unroll
        for (int i2=0;i2<4;i2++)
          xbv[(16*mt + q4*4 + i2)*136 + h*16 + l15] = f2b(o[i2]);
      }
    }
    __syncthreads();

    // ---- O-proj + residual
    {
      short8 a[2][4];
      #pragma unroll
      for (int mt=0;mt<2;mt++)
        #pragma unroll
        for (int kt=0;kt<4;kt++)
          a[mt][kt] = __builtin_bit_cast(short8, *(const uint4*)&xbv[(l15+16*mt)*136 + kt*32 + q4*8]);
      for (int i=0;i<2;i++){
        const int nt = w + 4*i;
        const int n  = nt*16 + l15;
        f32x4 a0 = {0.f,0.f,0.f,0.f}, a1 = {0.f,0.f,0.f,0.f};
        #pragma unroll
        for (int kt=0;kt<4;kt++){
          const short8 b = __builtin_bit_cast(short8, wfv[(96 + nt*4+kt)*64 + l]);
          a0 = MFMA16(a[0][kt], b, a0);
          a1 = MFMA16(a[1][kt], b, a1);
        }
        const float bias = boL[n];
        #pragma unroll
        for (int i2=0;i2<4;i2++){
          x32s[(q4*4+i2   )*132 + n] += a0[i2] + bias;
          x32s[(q4*4+i2+16)*132 + n] += a1[i2] + bias;
        }
      }
    }
    __syncthreads();
    ln_inplace(x32s, xbv, g1L, b1L, t);
    __syncthreads();

    // ---- FFN1 + relu
    {
      short8 a[2][4];
      #pragma unroll
      for (int mt=0;mt<2;mt++)
        #pragma unroll
        for (int kt=0;kt<4;kt++)
          a[mt][kt] = __builtin_bit_cast(short8, *(const uint4*)&xbv[(l15+16*mt)*136 + kt*32 + q4*8]);
      for (int i=0;i<4;i++){
        const int nt = w + 4*i;
        const int n  = nt*16 + l15;
        f32x4 a0 = {0.f,0.f,0.f,0.f}, a1 = {0.f,0.f,0.f,0.f};
        #pragma unroll
        for (int kt=0;kt<4;kt++){
          const short8 b = __builtin_bit_cast(short8, wfv[(128 + nt*4+kt)*64 + l]);
          a0 = MFMA16(a[0][kt], b, a0);
          a1 = MFMA16(a[1][kt], b, a1);
        }
        const float bias = bf1L[n];
        #pragma unroll
        for (int i2=0;i2<4;i2++){
          qk[(q4*4+i2   )*264 + n] = f2b(fmaxf(a0[i2]+bias, 0.f));
          qk[(q4*4+i2+16)*264 + n] = f2b(fmaxf(a1[i2]+bias, 0.f));
        }
      }
    }
    __syncthreads();

    // ---- FFN2 + residual, K=256
    {
      short8 a[2][8];
      #pragma unroll
      for (int mt=0;mt<2;mt++)
        #pragma unroll
        for (int kt=0;kt<8;kt++)
          a[mt][kt] = __builtin_bit_cast(short8, *(const uint4*)&qk[(l15+16*mt)*264 + kt*32 + q4*8]);
      for (int i=0;i<2;i++){
        const int nt = w + 4*i;
        const int n  = nt*16 + l15;
        f32x4 a0 = {0.f,0.f,0.f,0.f}, a1 = {0.f,0.f,0.f,0.f};
        #pragma unroll
        for (int kt=0;kt<8;kt++){
          const short8 b = __builtin_bit_cast(short8, wfv[(192 + nt*8+kt)*64 + l]);
          a0 = MFMA16(a[0][kt], b, a0);
          a1 = MFMA16(a[1][kt], b, a1);
        }
        const float bias = bf2L[n];
        #pragma unroll
        for (int i2=0;i2<4;i2++){
          x32s[(q4*4+i2   )*132 + n] += a0[i2] + bias;
          x32s[(q4*4+i2+16)*132 + n] += a1[i2] + bias;
        }
      }
    }
    __syncthreads();
    ln_inplace(x32s, xbv, g2L, b2L, t);
    __syncthreads();
  }

  // ---- epilogue: max-pool over the 32 tokens + fc
  if (t < CD){
    float m = -1e30f;
    #pragma unroll
    for (int k=0;k<CK;k++) m = fmaxf(m, x32s[k*132 + t]);
    pooled[t] = m;
  }
  __syncthreads();
  float acc = 0.f;
  const float* wr = fc_w + (size_t)t*CD;
  const float4* pp = (const float4*)pooled;
  #pragma unroll
  for (int i=0;i<CD/4;i++){
    const float4 w4 = *(const float4*)(wr + 4*i);
    const float4 p4 = pp[i];
    acc += p4.x*w4.x; acc += p4.y*w4.y; acc += p4.z*w4.z; acc += p4.w*w4.w;
  }
  acc += fc_b[t];
  const int b = g >> 9, s = g & 511;
  fcout[((size_t)b*CS + s)*CO + t] = acc;
}

// ---------------------------------------------------------------- linear interp S -> N
__global__ __launch_bounds__(256)
void interp_kernel(const float* __restrict__ fcout, float* __restrict__ out1)
{
  const int idx = blockIdx.x*256 + threadIdx.x;
  const int n  = idx & (CN-1);
  const int bo = idx >> 13;
  const int b  = bo >> 8, o = bo & 255;
  const double pos = (double)n * ((double)(CS-1)/(double)(CN-1));
  const int i0 = (int)pos;
  const int i1 = min(i0+1, CS-1);
  const float w = (float)(pos - (double)i0);
  const float v0 = fcout[((size_t)b*CS + i0)*CO + o];
  const float v1 = fcout[((size_t)b*CS + i1)*CO + o];
  out1[idx] = v0*(1.f - w) + v1*w;
}

// ---------------------------------------------------------------- launcher
extern "C" void kernel_launch(void* const* d_in, const int* in_sizes, int n_in,
                              void* d_out, int out_size, void* d_ws, size_t ws_size,
                              hipStream_t stream)
{
  (void)in_sizes; (void)n_in; (void)out_size;
  const float* xyz      = (const float*)d_in[0];
  const float* features = (const float*)d_in[1];
  const float* pe_w1    = (const float*)d_in[2];
  const float* pe_b1    = (const float*)d_in[3];
  const float* bn_g     = (const float*)d_in[4];
  const float* bn_b     = (const float*)d_in[5];
  const float* bn_m     = (const float*)d_in[6];
  const float* bn_v     = (const float*)d_in[7];
  const float* pe_w2    = (const float*)d_in[8];
  const float* pe_b2    = (const float*)d_in[9];
  const float* wqkv     = (const float*)d_in[10];
  const float* bqkv     = (const float*)d_in[11];
  const float* wo       = (const float*)d_in[12];
  const float* bo       = (const float*)d_in[13];
  const float* g1       = (const float*)d_in[14];
  const float* b1       = (const float*)d_in[15];
  const float* w1       = (const float*)d_in[16];
  const float* bf1      = (const float*)d_in[17];
  const float* w2       = (const float*)d_in[18];
  const float* bf2      = (const float*)d_in[19];
  const float* g2       = (const float*)d_in[20];
  const float* b2       = (const float*)d_in[21];
  const float* fc_w     = (const float*)d_in[22];
  const float* fc_b     = (const float*)d_in[23];

  char* ws = (char*)d_ws;
  int*    fps_idx = (int*)(ws);                               // 16 KB
  int*    gidx    = (int*)(ws + (16u<<10));                   // 512 KB
  ushort* wfrag   = (ushort*)(ws + (1u<<20));                 // 1 MB
  float*  xbuf    = (float*)(ws + (2u<<20));                  // 64 MB
  float*  fcout   = (float*)(ws + (66u<<20));                 // 4 MB
  float*  featT   = (float*)(ws + (70u<<20));                 // 32 MB (optional)
  const bool useT = ws_size >= ((size_t)102<<20);

  float* out0 = (float*)d_out;
  float* out1 = out0 + CB*3*CS;

  const int nblk = CB + 64 + (useT ? 2048 : 0);
  fps_fused_kernel<<<nblk, 1024, 0, stream>>>(xyz, fps_idx, features,
                                              useT ? featT : nullptr,
                                              wqkv, wo, w1, w2, wfrag);
  knn_kernel<<<CB*CS, 256, 0, stream>>>(xyz, fps_idx, gidx, out0);
  pe_kernel<<<CB*CS, 256, 0, stream>>>(xyz, features, useT ? featT : nullptr, gidx,
                                       pe_w1, pe_b1, bn_g, bn_b, bn_m, bn_v,
                                       pe_w2, pe_b2, xbuf);
  layers_mfma_kernel<<<CB*CS, 256, 0, stream>>>(xbuf, wfrag,
      bqkv, bo, g1, b1, bf1, bf2, g2, b2, fc_w, fc_b, fcout);
  interp_kernel<<<(CB*CO*CN)/256, 256, 0, stream>>>(fcout, out1);
}

// Round 9
// 1190.056 us; speedup vs baseline: 1.0787x; 1.0787x over previous
//
#include <hip/hip_runtime.h>
#include <math.h>

constexpr int CB  = 8;     // batches
constexpr int CN  = 8192;  // points
constexpr int CS  = 512;   // npoint
constexpr int CK  = 32;    // nsample
constexpr int CD  = 128;   // dim
constexpr int CF  = 256;   // dff
constexpr int CO  = 256;   // dim_out
constexpr float CEPS = 1e-5f;

typedef __attribute__((ext_vector_type(8)))  short short8;
typedef __attribute__((ext_vector_type(2)))  float f32x2;
typedef __attribute__((ext_vector_type(4)))  float f32x4;
typedef __attribute__((ext_vector_type(16))) float f32x16;
#define MFMA16(a,b,c) __builtin_amdgcn_mfma_f32_16x16x32_bf16(a,b,c,0,0,0)
#define MFMA32(a,b,c) __builtin_amdgcn_mfma_f32_32x32x16_bf16(a,b,c,0,0,0)

__device__ __forceinline__ ushort f2b(float f){
  unsigned u = __builtin_bit_cast(unsigned, f);
  u = u + 0x7fffu + ((u >> 16) & 1u);
  return (ushort)(u >> 16);
}

// DPP permute of a u64, masked lanes keep their own value (old = self).
template<int CTRL, int RM>
__device__ __forceinline__ unsigned long long dpp64(unsigned long long k){
  int lo = (int)(unsigned)k;
  int hi = (int)(unsigned)(k >> 32);
  int plo = __builtin_amdgcn_update_dpp(lo, lo, CTRL, RM, 0xF, false);
  int phi = __builtin_amdgcn_update_dpp(hi, hi, CTRL, RM, 0xF, false);
  return ((unsigned long long)(unsigned)phi << 32) | (unsigned)plo;
}
// full-wave max; result valid in lane 63
__device__ __forceinline__ unsigned long long wave_max64(unsigned long long k){
  unsigned long long p;
  p = dpp64<0xB1,0xF>(k); k = p > k ? p : k;   // i^1
  p = dpp64<0x4E,0xF>(k); k = p > k ? p : k;   // i^2
  p = dpp64<0x140,0xF>(k); k = p > k ? p : k;  // row mirror
  p = dpp64<0x141,0xF>(k); k = p > k ? p : k;  // half mirror -> row(16) max everywhere
  p = dpp64<0x142,0xA>(k); k = p > k ? p : k;  // bcast15 -> rows 1,3
  p = dpp64<0x143,0xC>(k); k = p > k ? p : k;  // bcast31 -> rows 2,3 ; lane63 full
  return k;
}
__device__ __forceinline__ unsigned long long wave_min64(unsigned long long k){
  unsigned long long p;
  p = dpp64<0xB1,0xF>(k); k = p < k ? p : k;
  p = dpp64<0x4E,0xF>(k); k = p < k ? p : k;
  p = dpp64<0x140,0xF>(k); k = p < k ? p : k;
  p = dpp64<0x141,0xF>(k); k = p < k ? p : k;
  p = dpp64<0x142,0xA>(k); k = p < k ? p : k;
  p = dpp64<0x143,0xC>(k); k = p < k ? p : k;
  return k;
}
// butterfly over 8 replicated values in lanes (l&7) -> all lanes get extreme
__device__ __forceinline__ unsigned long long oct_max64(unsigned long long k){
  unsigned long long p;
  p = dpp64<0xB1,0xF>(k); k = p > k ? p : k;
  p = dpp64<0x4E,0xF>(k); k = p > k ? p : k;
  p = dpp64<0x141,0xF>(k); k = p > k ? p : k;  // i^7 crosses the 4-groups
  return k;
}
__device__ __forceinline__ unsigned long long quad_min64(unsigned long long k){
  unsigned long long p;
  p = dpp64<0xB1,0xF>(k); k = p < k ? p : k;
  p = dpp64<0x4E,0xF>(k); k = p < k ? p : k;
  return k;
}

// ---------------------------------------------------------------- FPS + wprep + transpose fused
// blocks 0..7: FPS (512 thr, 16 pts in float2 pairs -> packed-FP32 update).
// blocks 8..135: weight prep. blocks 136+: feature transpose (riders).
__global__ __launch_bounds__(512)
void fps_fused_kernel(const float* __restrict__ xyz, int* __restrict__ fps_idx,
                      const float* __restrict__ features, float* __restrict__ featT,
                      const float* __restrict__ wqkv, const float* __restrict__ wo,
                      const float* __restrict__ w1,   const float* __restrict__ w2,
                      ushort* __restrict__ wfrag)
{
#pragma clang fp contract(off)
  __shared__ __align__(16) float4 p4[CN];
  __shared__ unsigned long long wred[2][8];
  const int bid = blockIdx.x, t = threadIdx.x;

  if (bid >= CB + 128){
    // ---- transpose role: 2 tiles of 32x32 per 512-thread block
    if (featT == nullptr) return;
    const int tt  = (bid - CB - 128)*2 + (t >> 8);
    const int b2  = tt >> 10;
    const int rem = tt & 1023;
    const int d0  = (rem >> 8) * 32;
    const int n0  = (rem & 255) * 32;
    const int t2  = t & 255;
    const int tx  = t2 & 31, ty = t2 >> 5;     // ty in 0..7
    float* tl = ((float*)p4) + (t >> 8) * (32*33);
    const float* fb = features + (size_t)b2*CD*CN;
    #pragma unroll
    for (int r=0;r<32;r+=8) tl[(ty+r)*33 + tx] = fb[(size_t)(d0+ty+r)*CN + n0+tx];
    __syncthreads();
    float* ftb = featT + (size_t)b2*CN*CD;
    #pragma unroll
    for (int r=0;r<32;r+=8) ftb[(size_t)(n0+ty+r)*CD + d0+tx] = tl[tx*33 + (ty+r)];
    return;
  }
  if (bid >= CB){
    // ---- weight prep role -> bf16 MFMA B-fragments
    const int tid = (bid - CB)*512 + t;        // 0..65535
    const int l = tid & 63;
    const int f = tid >> 6;                    // 0..1023
    const int L = f >> 8;
    const int r = f & 255;
    const float* src; int stride, nt, kt;
    if (r < 96)      { nt = r>>2;        kt = r&3;        src = wqkv + (size_t)L*384*128; stride = 128; }
    else if (r < 128){ nt = (r-96)>>2;   kt = (r-96)&3;   src = wo   + (size_t)L*128*128; stride = 128; }
    else if (r < 192){ nt = (r-128)>>2;  kt = (r-128)&3;  src = w1   + (size_t)L*256*128; stride = 128; }
    else             { nt = (r-192)>>3;  kt = (r-192)&7;  src = w2   + (size_t)L*128*256; stride = 256; }
    const int n = nt*16 + (l & 15);
    const int k = kt*32 + (l >> 4)*8;
    const float* p = src + (size_t)n*stride + k;
    uint4 o;
    o.x = (unsigned)f2b(p[0]) | ((unsigned)f2b(p[1])<<16);
    o.y = (unsigned)f2b(p[2]) | ((unsigned)f2b(p[3])<<16);
    o.z = (unsigned)f2b(p[4]) | ((unsigned)f2b(p[5])<<16);
    o.w = (unsigned)f2b(p[6]) | ((unsigned)f2b(p[7])<<16);
    *(uint4*)(wfrag + (size_t)tid*8) = o;
    return;
  }

  // ---- FPS role: 512 thr x 16 pts (8 float2 pairs); DPP wave reduce; one barrier/iter.
  const int b = bid;
  const int w = t >> 6, lane = t & 63;
  const float* xb = xyz + (size_t)b*3*CN;
  f32x2 px[8], py[8], pz[8], dist[8];
  unsigned ilo[16];
  #pragma unroll
  for (int u=0;u<8;u++){
    const int i0 = t + 512*(2*u);
    const int i1 = t + 512*(2*u+1);
    px[u] = f32x2{xb[i0],      xb[i1]};
    py[u] = f32x2{xb[CN+i0],   xb[CN+i1]};
    pz[u] = f32x2{xb[2*CN+i0], xb[2*CN+i1]};
    dist[u] = f32x2{1e10f, 1e10f};
    ilo[2*u]   = (unsigned)(8191 - i0);
    ilo[2*u+1] = (unsigned)(8191 - i1);
    p4[i0] = make_float4(px[u][0], py[u][0], pz[u][0], 0.f);
    p4[i1] = make_float4(px[u][1], py[u][1], pz[u][1], 0.f);
  }
  __syncthreads();
  int far = 0, par = 0;
  float4 c = p4[0];
  for (int it = 0; it < CS; ++it){
    if (t == 0) fps_idx[b*CS + it] = far;
    unsigned long long kk[16];
    const f32x2 cx2 = {c.x, c.x}, cy2 = {c.y, c.y}, cz2 = {c.z, c.z};
    #pragma unroll
    for (int u=0;u<8;u++){
      const f32x2 dx = px[u] - cx2;          // packed sub
      const f32x2 dy = py[u] - cy2;
      const f32x2 dz = pz[u] - cz2;
      const f32x2 d2 = (dx*dx + dy*dy) + dz*dz;   // packed mul/add, contract off
      const float nd0 = fminf(dist[u][0], d2[0]);
      const float nd1 = fminf(dist[u][1], d2[1]);
      dist[u] = f32x2{nd0, nd1};
      kk[2*u]   = ((unsigned long long)__builtin_bit_cast(unsigned, nd0) << 32) | ilo[2*u];
      kk[2*u+1] = ((unsigned long long)__builtin_bit_cast(unsigned, nd1) << 32) | ilo[2*u+1];
    }
    #pragma unroll
    for (int st=1; st<16; st<<=1)
      #pragma unroll
      for (int j=0;j<16;j+=2*st)
        kk[j] = kk[j] >= kk[j+st] ? kk[j] : kk[j+st];
    const unsigned long long key = wave_max64(kk[0]);
    if (lane == 63) wred[par][w] = key;          // result lives in lane 63; no shfl
    __syncthreads();
    unsigned long long k2 = wred[par][lane & 7];
    k2 = oct_max64(k2);
    far = 8191 - (int)(k2 & 0xFFFFFFFFu);
    c = p4[far];
    par ^= 1;
  }
}

// ---------------------------------------------------------------- kNN (+ new_xyz output folded in)
__global__ __launch_bounds__(256)
void knn_kernel(const float* __restrict__ xyz, const int* __restrict__ fps_idx,
                int* __restrict__ gidx, float* __restrict__ out0)
{
#pragma clang fp contract(off)
  __shared__ unsigned long long wredk[2][4];
  const int blk = blockIdx.x, t = threadIdx.x;
  const int w = t >> 6, l = t & 63;
  const int b = blk >> 9;
  const int s = blk & 511;
  const float* xb = xyz + (size_t)b*3*CN;
  const int cidx = fps_idx[b*CS + s];
  const float cx = xb[cidx], cy = xb[CN+cidx], cz = xb[2*CN+cidx];
  const float cn2 = (cx*cx + cy*cy) + cz*cz;
  if (t == 0){
    float* o = out0 + (size_t)b*3*CS + s;
    o[0] = cx; o[CS] = cy; o[2*CS] = cz;
  }
  unsigned long long kv[32];
  #pragma unroll
  for (int j=0;j<32;j++){
    const int i = t + 256*j;
    const float x = xb[i], y = xb[CN+i], z = xb[2*CN+i];
    const float pn2 = (x*x + y*y) + z*z;
    const float dot = (cx*x + cy*y) + cz*z;
    const float d2 = (cn2 + pn2) - 2.0f*dot;
    unsigned u = __builtin_bit_cast(unsigned, d2);
    u ^= (unsigned)((int)u >> 31) | 0x80000000u;   // total order incl. negatives
    kv[j] = ((unsigned long long)u << 32) | (unsigned)i;
  }
  unsigned long long mv;
  {
    unsigned long long tmp[16];
    #pragma unroll
    for (int j=0;j<16;j++) tmp[j] = kv[j] < kv[j+16] ? kv[j] : kv[j+16];
    #pragma unroll
    for (int st=8; st>=1; st>>=1)
      #pragma unroll
      for (int j=0;j<st;j++) tmp[j] = tmp[j] < tmp[j+st] ? tmp[j] : tmp[j+st];
    mv = tmp[0];
  }
  int par = 0;
  for (int k=0;k<CK;k++){
    const unsigned long long v = wave_min64(mv);
    if (l == 63) wredk[par][w] = v;              // no shfl
    __syncthreads();
    unsigned long long k2 = wredk[par][l & 3];
    k2 = quad_min64(k2);
    const int win = (int)(k2 & 0xFFFFFFFFu);
    if (t == 0) gidx[(size_t)blk*CK + k] = win;
    if ((win & 255) == t){
      const int jw = win >> 8;
      #pragma unroll
      for (int j=0;j<32;j++) if (j == jw) kv[j] = ~0ull;
      unsigned long long tmp[16];
      #pragma unroll
      for (int j=0;j<16;j++) tmp[j] = kv[j] < kv[j+16] ? kv[j] : kv[j+16];
      #pragma unroll
      for (int st=8; st>=1; st>>=1)
        #pragma unroll
        for (int j=0;j<st;j++) tmp[j] = tmp[j] < tmp[j+st] ? tmp[j] : tmp[j+st];
      mv = tmp[0];
    }
    par ^= 1;
  }
}

// ---------------------------------------------------------------- gather + PE (4x4 register tile)
// w2s layout: [128 rows][64 dwords], float4-unit u stored at u ^ ((row>>2)&7).
// Read lane-stride was 16-way bank conflicted with linear 68-pad; swizzle -> 4-way.
__global__ __launch_bounds__(256)
void pe_kernel(const float* __restrict__ xyz, const float* __restrict__ features,
               const float* __restrict__ featT, const int* __restrict__ gidx,
               const float* __restrict__ pe_w1, const float* __restrict__ pe_b1,
               const float* __restrict__ bn_g, const float* __restrict__ bn_b,
               const float* __restrict__ bn_m, const float* __restrict__ bn_v,
               const float* __restrict__ pe_w2, const float* __restrict__ pe_b2,
               float* __restrict__ xout)
{
  __shared__ __align__(16) float w2s[CD*64];
  __shared__ __align__(16) float hr[CK*68];
  __shared__ int idxs[CK];
  __shared__ float gx[CK], gy[CK], gz[CK];
  const int g = blockIdx.x, t = threadIdx.x;
  const int b = g >> 9;
  for (int i=t; i<CD*64; i+=256){
    const int row = i>>6, c = i&63;
    const int u = (c>>2) ^ ((row>>2)&7);
    w2s[row*64 + (u<<2) + (c&3)] = pe_w2[i];
  }
  if (t < CK){
    const int id = gidx[(size_t)g*CK + t];
    idxs[t] = id;
    const float* xb = xyz + (size_t)b*3*CN;
    gx[t] = xb[id]; gy[t] = xb[CN+id]; gz[t] = xb[2*CN+id];
  }
  __syncthreads();
  for (int v=t; v<CK*64; v+=256){
    const int k = v>>6, j = v&63;
    float h = ((gx[k]*pe_w1[j*3] + gy[k]*pe_w1[j*3+1]) + gz[k]*pe_w1[j*3+2]) + pe_b1[j];
    h = (h - bn_m[j]) / sqrtf(bn_v[j] + CEPS) * bn_g[j] + bn_b[j];
    hr[k*68+j] = fmaxf(h, 0.f);
  }
  __syncthreads();
  const int kt = t >> 5, dt = t & 31;
  const int k0 = kt*4, d0 = dt*4;
  const int sw = dt & 7;                 // = ((d0+bb)>>2)&7 for bb in 0..3
  float acc[4][4];
  #pragma unroll
  for (int a=0;a<4;a++)
    #pragma unroll
    for (int bb=0;bb<4;bb++) acc[a][bb] = 0.f;
  for (int j=0;j<16;j++){
    float4 h4[4], w4[4];
    #pragma unroll
    for (int a=0;a<4;a++) h4[a] = *(const float4*)&hr[(k0+a)*68 + j*4];
    #pragma unroll
    for (int bb=0;bb<4;bb++) w4[bb] = *(const float4*)&w2s[(d0+bb)*64 + ((j ^ sw)<<2)];
    #pragma unroll
    for (int a=0;a<4;a++)
      #pragma unroll
      for (int bb=0;bb<4;bb++){
        acc[a][bb] += h4[a].x*w4[bb].x; acc[a][bb] += h4[a].y*w4[bb].y;
        acc[a][bb] += h4[a].z*w4[bb].z; acc[a][bb] += h4[a].w*w4[bb].w;
      }
  }
  const float4 b2v = *(const float4*)&pe_b2[d0];
  const float* fb  = features + (size_t)b*CD*CN;
  const float* ftb = featT ? (featT + (size_t)b*CN*CD) : nullptr;
  #pragma unroll
  for (int a=0;a<4;a++){
    const int id = idxs[k0+a];
    float4 gf;
    if (ftb) gf = *(const float4*)&ftb[(size_t)id*CD + d0];
    else gf = make_float4(fb[(size_t)(d0+0)*CN+id], fb[(size_t)(d0+1)*CN+id],
                          fb[(size_t)(d0+2)*CN+id], fb[(size_t)(d0+3)*CN+id]);
    float4 o;
    o.x = gf.x + (acc[a][0] + b2v.x);
    o.y = gf.y + (acc[a][1] + b2v.y);
    o.z = gf.z + (acc[a][2] + b2v.z);
    o.w = gf.w + (acc[a][3] + b2v.w);
    *(float4*)&xout[(size_t)g*4096 + (size_t)(k0+a)*128 + d0] = o;
  }
}

// ---------------------------------------------------------------- fused MFMA transformer: 4 layers + pool + fc
__device__ __forceinline__ void ln_inplace(float* x32s, ushort* xbv,
                                           const float* __restrict__ gamma,
                                           const float* __restrict__ beta, int t)
{
  const int r = t >> 3, j = t & 7;
  float v[16]; float s = 0.f;
  #pragma unroll
  for (int i=0;i<16;i++){ v[i] = x32s[r*132 + j + 8*i]; s += v[i]; }
  #pragma unroll
  for (int off=1; off<8; off<<=1) s += __shfl_xor(s, off);
  const float mean = s * (1.f/128.f);
  float var = 0.f;
  #pragma unroll
  for (int i=0;i<16;i++){ const float d = v[i]-mean; var += d*d; }
  #pragma unroll
  for (int off=1; off<8; off<<=1) var += __shfl_xor(var, off);
  const float inv = 1.f / sqrtf(var*(1.f/128.f) + CEPS);
  #pragma unroll
  for (int i=0;i<16;i++){
    const int d = j + 8*i;
    const float o = (v[i]-mean)*inv*gamma[d] + beta[d];
    x32s[r*132 + d] = o;
    xbv[r*136 + d] = f2b(o);
  }
}

__global__ __launch_bounds__(256, 2)
void layers_mfma_kernel(const float* __restrict__ xbuf, const ushort* __restrict__ wf,
                        const float* __restrict__ bqkv, const float* __restrict__ bo,
                        const float* __restrict__ g1, const float* __restrict__ b1v,
                        const float* __restrict__ bf1, const float* __restrict__ bf2,
                        const float* __restrict__ g2, const float* __restrict__ b2v,
                        const float* __restrict__ fc_w, const float* __restrict__ fc_b,
                        float* __restrict__ fcout)
{
  __shared__ __align__(16) float  x32s[32*132];   // fp32 residual path
  __shared__ __align__(16) ushort xbv [32*136];   // bf16 A-operand buffer
  __shared__ __align__(16) ushort qk  [32*264];   // Q|K, later FFN1 out
  __shared__ __align__(16) ushort vT  [128*40];   // V transposed [dim][token]
  __shared__ __align__(16) ushort Pb  [4*32*40];  // per-wave P scratch
  __shared__ __align__(16) float  pooled[CD];
  const int g = blockIdx.x, t = threadIdx.x;
  const int w = t>>6, l = t&63;
  const int l15 = l&15, q4 = l>>4, l31 = l&31, hi = l>>5;
  const float* xg = xbuf + (size_t)g*1024*4;

  for (int i=t;i<1024;i+=256){
    const float4 v = ((const float4*)xg)[i];
    const int r = i>>5, c = (i&31)*4;
    *(float4*)&x32s[r*132 + c] = v;
    uint2 p;
    p.x = (unsigned)f2b(v.x) | ((unsigned)f2b(v.y)<<16);
    p.y = (unsigned)f2b(v.z) | ((unsigned)f2b(v.w)<<16);
    *(uint2*)&xbv[r*136 + c] = p;
  }
  __syncthreads();

  #pragma unroll 1
  for (int L = 0; L < 4; ++L){
    const uint4*  wfv   = (const uint4*)(wf + (size_t)L*131072);
    const float* bqkvL  = bqkv + (size_t)L*3*CD;
    const float* boL    = bo   + (size_t)L*CD;
    const float* g1L    = g1   + (size_t)L*CD;
    const float* b1L    = b1v  + (size_t)L*CD;
    const float* bf1L   = bf1  + (size_t)L*CF;
    const float* bf2L   = bf2  + (size_t)L*CD;
    const float* g2L    = g2   + (size_t)L*CD;
    const float* b2L    = b2v  + (size_t)L*CD;

    // ---- QKV
    {
      short8 a[2][4];
      #pragma unroll
      for (int mt=0;mt<2;mt++)
        #pragma unroll
        for (int kt=0;kt<4;kt++)
          a[mt][kt] = __builtin_bit_cast(short8, *(const uint4*)&xbv[(l15+16*mt)*136 + kt*32 + q4*8]);
      for (int i=0;i<6;i++){
        const int nt = w + 4*i;
        const int n  = nt*16 + l15;
        f32x4 a0 = {0.f,0.f,0.f,0.f}, a1 = {0.f,0.f,0.f,0.f};
        #pragma unroll
        for (int kt=0;kt<4;kt++){
          const short8 b = __builtin_bit_cast(short8, wfv[(nt*4+kt)*64 + l]);
          a0 = MFMA16(a[0][kt], b, a0);
          a1 = MFMA16(a[1][kt], b, a1);
        }
        const float bias = bqkvL[n];
        if (nt < 16){
          #pragma unroll
          for (int i2=0;i2<4;i2++){
            qk[(q4*4+i2   )*264 + n] = f2b(a0[i2]+bias);
            qk[(q4*4+i2+16)*264 + n] = f2b(a1[i2]+bias);
          }
        } else {
          const int d = n - 256;
          uint2 p0, p1;
          p0.x = (unsigned)f2b(a0[0]+bias) | ((unsigned)f2b(a0[1]+bias)<<16);
          p0.y = (unsigned)f2b(a0[2]+bias) | ((unsigned)f2b(a0[3]+bias)<<16);
          p1.x = (unsigned)f2b(a1[0]+bias) | ((unsigned)f2b(a1[1]+bias)<<16);
          p1.y = (unsigned)f2b(a1[2]+bias) | ((unsigned)f2b(a1[3]+bias)<<16);
          *(uint2*)&vT[d*40 + q4*4]      = p0;
          *(uint2*)&vT[d*40 + 16 + q4*4] = p1;
        }
      }
    }
    __syncthreads();

    // ---- attention
    for (int hh=0; hh<2; hh++){
      const int h = 2*w + hh;
      const short8 ka = __builtin_bit_cast(short8, *(const uint4*)&qk[l31*264 + 128 + h*16 + hi*8]);
      const short8 qb = __builtin_bit_cast(short8, *(const uint4*)&qk[l31*264 +       h*16 + hi*8]);
      f32x16 s;
      #pragma unroll
      for (int i=0;i<16;i++) s[i] = 0.f;
      s = MFMA32(ka, qb, s);
      float e[16]; float mx = -1e30f;
      #pragma unroll
      for (int i=0;i<16;i++){ e[i] = s[i]*0.25f; mx = fmaxf(mx, e[i]); }
      mx = fmaxf(mx, __shfl_xor(mx, 32));
      float sum = 0.f;
      #pragma unroll
      for (int i=0;i<16;i++){ e[i] = __expf(e[i]-mx); sum += e[i]; }
      sum += __shfl_xor(sum, 32);
      const float inv = 1.f/sum;
      #pragma unroll
      for (int j=0;j<4;j++){
        uint2 p;
        p.x = (unsigned)f2b(e[4*j  ]*inv) | ((unsigned)f2b(e[4*j+1]*inv)<<16);
        p.y = (unsigned)f2b(e[4*j+2]*inv) | ((unsigned)f2b(e[4*j+3]*inv)<<16);
        *(uint2*)&Pb[w*1280 + l31*40 + j*8 + hi*4] = p;
      }
      const short8 bv = __builtin_bit_cast(short8, *(const uint4*)&vT[(h*16+l15)*40 + q4*8]);
      #pragma unroll
      for (int mt=0;mt<2;mt++){
        const short8 ap = __builtin_bit_cast(short8, *(const uint4*)&Pb[w*1280 + (l15+16*mt)*40 + q4*8]);
        f32x4 o = {0.f,0.f,0.f,0.f};
        o = MFMA16(ap, bv, o);
        #pragma unroll
        for (int i2=0;i2<4;i2++)
          xbv[(16*mt + q4*4 + i2)*136 + h*16 + l15] = f2b(o[i2]);
      }
    }
    __syncthreads();

    // ---- O-proj + residual
    {
      short8 a[2][4];
      #pragma unroll
      for (int mt=0;mt<2;mt++)
        #pragma unroll
        for (int kt=0;kt<4;kt++)
          a[mt][kt] = __builtin_bit_cast(short8, *(const uint4*)&xbv[(l15+16*mt)*136 + kt*32 + q4*8]);
      for (int i=0;i<2;i++){
        const int nt = w + 4*i;
        const int n  = nt*16 + l15;
        f32x4 a0 = {0.f,0.f,0.f,0.f}, a1 = {0.f,0.f,0.f,0.f};
        #pragma unroll
        for (int kt=0;kt<4;kt++){
          const short8 b = __builtin_bit_cast(short8, wfv[(96 + nt*4+kt)*64 + l]);
          a0 = MFMA16(a[0][kt], b, a0);
          a1 = MFMA16(a[1][kt], b, a1);
        }
        const float bias = boL[n];
        #pragma unroll
        for (int i2=0;i2<4;i2++){
          x32s[(q4*4+i2   )*132 + n] += a0[i2] + bias;
          x32s[(q4*4+i2+16)*132 + n] += a1[i2] + bias;
        }
      }
    }
    __syncthreads();
    ln_inplace(x32s, xbv, g1L, b1L, t);
    __syncthreads();

    // ---- FFN1 + relu
    {
      short8 a[2][4];
      #pragma unroll
      for (int mt=0;mt<2;mt++)
        #pragma unroll
        for (int kt=0;kt<4;kt++)
          a[mt][kt] = __builtin_bit_cast(short8, *(const uint4*)&xbv[(l15+16*mt)*136 + kt*32 + q4*8]);
      for (int i=0;i<4;i++){
        const int nt = w + 4*i;
        const int n  = nt*16 + l15;
        f32x4 a0 = {0.f,0.f,0.f,0.f}, a1 = {0.f,0.f,0.f,0.f};
        #pragma unroll
        for (int kt=0;kt<4;kt++){
          const short8 b = __builtin_bit_cast(short8, wfv[(128 + nt*4+kt)*64 + l]);
          a0 = MFMA16(a[0][kt], b, a0);
          a1 = MFMA16(a[1][kt], b, a1);
        }
        const float bias = bf1L[n];
        #pragma unroll
        for (int i2=0;i2<4;i2++){
          qk[(q4*4+i2   )*264 + n] = f2b(fmaxf(a0[i2]+bias, 0.f));
          qk[(q4*4+i2+16)*264 + n] = f2b(fmaxf(a1[i2]+bias, 0.f));
        }
      }
    }
    __syncthreads();

    // ---- FFN2 + residual, K=256
    {
      short8 a[2][8];
      #pragma unroll
      for (int mt=0;mt<2;mt++)
        #pragma unroll
        for (int kt=0;kt<8;kt++)
          a[mt][kt] = __builtin_bit_cast(short8, *(const uint4*)&qk[(l15+16*mt)*264 + kt*32 + q4*8]);
      for (int i=0;i<2;i++){
        const int nt = w + 4*i;
        const int n  = nt*16 + l15;
        f32x4 a0 = {0.f,0.f,0.f,0.f}, a1 = {0.f,0.f,0.f,0.f};
        #pragma unroll
        for (int kt=0;kt<8;kt++){
          const short8 b = __builtin_bit_cast(short8, wfv[(192 + nt*8+kt)*64 + l]);
          a0 = MFMA16(a[0][kt], b, a0);
          a1 = MFMA16(a[1][kt], b, a1);
        }
        const float bias = bf2L[n];
        #pragma unroll
        for (int i2=0;i2<4;i2++){
          x32s[(q4*4+i2   )*132 + n] += a0[i2] + bias;
          x32s[(q4*4+i2+16)*132 + n] += a1[i2] + bias;
        }
      }
    }
    __syncthreads();
    ln_inplace(x32s, xbv, g2L, b2L, t);
    __syncthreads();
  }

  // ---- epilogue: max-pool over the 32 tokens + fc
  if (t < CD){
    float m = -1e30f;
    #pragma unroll
    for (int k=0;k<CK;k++) m = fmaxf(m, x32s[k*132 + t]);
    pooled[t] = m;
  }
  __syncthreads();
  float acc = 0.f;
  const float* wr = fc_w + (size_t)t*CD;
  const float4* pp = (const float4*)pooled;
  #pragma unroll
  for (int i=0;i<CD/4;i++){
    const float4 w4 = *(const float4*)(wr + 4*i);
    const float4 p4 = pp[i];
    acc += p4.x*w4.x; acc += p4.y*w4.y; acc += p4.z*w4.z; acc += p4.w*w4.w;
  }
  acc += fc_b[t];
  const int b = g >> 9, s = g & 511;
  fcout[((size_t)b*CS + s)*CO + t] = acc;
}

// ---------------------------------------------------------------- linear interp S -> N
__global__ __launch_bounds__(256)
void interp_kernel(const float* __restrict__ fcout, float* __restrict__ out1)
{
  const int idx = blockIdx.x*256 + threadIdx.x;
  const int n  = idx & (CN-1);
  const int bo = idx >> 13;
  const int b  = bo >> 8, o = bo & 255;
  const double pos = (double)n * ((double)(CS-1)/(double)(CN-1));
  const int i0 = (int)pos;
  const int i1 = min(i0+1, CS-1);
  const float w = (float)(pos - (double)i0);
  const float v0 = fcout[((size_t)b*CS + i0)*CO + o];
  const float v1 = fcout[((size_t)b*CS + i1)*CO + o];
  out1[idx] = v0*(1.f - w) + v1*w;
}

// ---------------------------------------------------------------- launcher
extern "C" void kernel_launch(void* const* d_in, const int* in_sizes, int n_in,
                              void* d_out, int out_size, void* d_ws, size_t ws_size,
                              hipStream_t stream)
{
  (void)in_sizes; (void)n_in; (void)out_size;
  const float* xyz      = (const float*)d_in[0];
  const float* features = (const float*)d_in[1];
  const float* pe_w1    = (const float*)d_in[2];
  const float* pe_b1    = (const float*)d_in[3];
  const float* bn_g     = (const float*)d_in[4];
  const float* bn_b     = (const float*)d_in[5];
  const float* bn_m     = (const float*)d_in[6];
  const float* bn_v     = (const float*)d_in[7];
  const float* pe_w2    = (const float*)d_in[8];
  const float* pe_b2    = (const float*)d_in[9];
  const float* wqkv     = (const float*)d_in[10];
  const float* bqkv     = (const float*)d_in[11];
  const float* wo       = (const float*)d_in[12];
  const float* bo       = (const float*)d_in[13];
  const float* g1       = (const float*)d_in[14];
  const float* b1       = (const float*)d_in[15];
  const float* w1       = (const float*)d_in[16];
  const float* bf1      = (const float*)d_in[17];
  const float* w2       = (const float*)d_in[18];
  const float* bf2      = (const float*)d_in[19];
  const float* g2       = (const float*)d_in[20];
  const float* b2       = (const float*)d_in[21];
  const float* fc_w     = (const float*)d_in[22];
  const float* fc_b     = (const float*)d_in[23];

  char* ws = (char*)d_ws;
  int*    fps_idx = (int*)(ws);                               // 16 KB
  int*    gidx    = (int*)(ws + (16u<<10));                   // 512 KB
  ushort* wfrag   = (ushort*)(ws + (1u<<20));                 // 1 MB
  float*  xbuf    = (float*)(ws + (2u<<20));                  // 64 MB
  float*  fcout   = (float*)(ws + (66u<<20));                 // 4 MB
  float*  featT   = (float*)(ws + (70u<<20));                 // 32 MB (optional)
  const bool useT = ws_size >= ((size_t)102<<20);

  float* out0 = (float*)d_out;
  float* out1 = out0 + CB*3*CS;

  const int nblk = CB + 128 + (useT ? 4096 : 0);
  fps_fused_kernel<<<nblk, 512, 0, stream>>>(xyz, fps_idx, features,
                                             useT ? featT : nullptr,
                                             wqkv, wo, w1, w2, wfrag);
  knn_kernel<<<CB*CS, 256, 0, stream>>>(xyz, fps_idx, gidx, out0);
  pe_kernel<<<CB*CS, 256, 0, stream>>>(xyz, features, useT ? featT : nullptr, gidx,
                                       pe_w1, pe_b1, bn_g, bn_b, bn_m, bn_v,
                                       pe_w2, pe_b2, xbuf);
  layers_mfma_kernel<<<CB*CS, 256, 0, stream>>>(xbuf, wfrag,
      bqkv, bo, g1, b1, bf1, bf2, g2, b2, fc_w, fc_b, fcout);
  interp_kernel<<<(CB*CO*CN)/256, 256, 0, stream>>>(fcout, out1);
}